// Round 18
// baseline (122.734 us; speedup 1.0000x reference)
//
#include <hip/hip_runtime.h>
#include <math.h>

typedef __attribute__((ext_vector_type(8))) short bf16x8;
typedef __attribute__((ext_vector_type(4))) float f32x4;
typedef unsigned short u16;

__device__ __forceinline__ unsigned short f2bf(float f) {
    unsigned u = __builtin_bit_cast(unsigned, f);
    u += 0x7fffu + ((u >> 16) & 1u);          // round-to-nearest-even
    return (unsigned short)(u >> 16);
}

// ---------------------------------------------------------------------------
// Fused prep: one kernel, 512 blocks x 128 threads.
//  b < 384 : build row r of mesh s (t<64 active) via register+shuffle layer
//            composition, sincos computed INLINE with a 4-deep mzi prefetch
//            (replaces the separate trig-table kernel + its launch gap).
//  b >= 384: pack P4 from W (n = b-384, j = t).
// P1: [256 cols][128 k]; P2,P3: [256 cols][256 k]; P4: [128 cols][256 k].
// ---------------------------------------------------------------------------
__global__ __launch_bounds__(128) void prep_all_kernel(
    const float* __restrict__ mzi1, const float* __restrict__ mzi2,
    const float* __restrict__ mzi3, const float* __restrict__ inph,
    const float* __restrict__ outph1, const float* __restrict__ outph2,
    const float* __restrict__ outph3, const float* __restrict__ W,
    u16* __restrict__ P1, u16* __restrict__ P2, u16* __restrict__ P3,
    u16* __restrict__ P4)
{
    const int b = blockIdx.x, t = threadIdx.x;

    if (b >= 384) {                    // ---- P4 pack path ----
        const int n = b - 384;         // output col 0..127
        const int j = t;               // complex feature 0..127
        const int rre = ((j >> 4) * 32) + (j & 15);
        P4[n * 256 + rre]      = f2bf(W[n * 256 + j]);
        P4[n * 256 + rre + 16] = f2bf(W[n * 256 + j + 128]);
        return;
    }
    if (t >= 64) return;               // ---- build path: one wave ----

    const int s = b >> 7, r = b & 127;
    const float* mzi = (s == 0) ? mzi1 : ((s == 1) ? mzi2 : mzi3);

    float2 a = make_float2(0.f, 0.f), b2 = make_float2(0.f, 0.f);
    if (s == 0) {
        float sp, cp; __sincosf(inph[r], &sp, &cp);
        if (2 * t == r)     a  = make_float2(cp, sp);
        if (2 * t + 1 == r) b2 = make_float2(cp, sp);
    } else {
        if (2 * t == r)     a.x  = 1.f;
        if (2 * t + 1 == r) b2.x = 1.f;
    }

    // 4-deep prefetch of raw {theta, phi} for this thread's MZI slot
    auto ldmz = [&](int L) -> float2 {
        const int start = L & 1;
        const int m = 64 - start;                     // (128-start)>>1
        if (t < m) {
            const int off = (L >> 1) * 254 + start * 128 + 2 * t;
            return *(const float2*)(mzi + off);
        }
        return make_float2(0.f, 0.f);                 // identity MZI
    };
    float2 mz[4];
    #pragma unroll
    for (int i = 0; i < 4; ++i) mz[i] = ldmz(i);

    #pragma unroll 4
    for (int L = 0; L < 128; ++L) {
        const float2 v = mz[L & 3];
        if (L < 124) mz[L & 3] = ldmz(L + 4);
        float st, ct, sp, cp;
        __sincosf(v.x, &st, &ct);
        __sincosf(v.y, &sp, &cp);
        if ((L & 1) == 0) {
            float pr = ct * (a.x * cp - a.y * sp) + st * b2.x;
            float pi = ct * (a.x * sp + a.y * cp) + st * b2.y;
            float qr = st * a.x - ct * (b2.x * cp + b2.y * sp);
            float qi = st * a.y - ct * (b2.y * cp - b2.x * sp);
            a = make_float2(pr, pi); b2 = make_float2(qr, qi);
        } else {
            float2 an;
            an.x = __shfl_down(a.x, 1); an.y = __shfl_down(a.y, 1);
            float pr = ct * (b2.x * cp - b2.y * sp) + st * an.x;
            float pi = ct * (b2.x * sp + b2.y * cp) + st * an.y;
            float qr = st * b2.x - ct * (an.x * cp + an.y * sp);
            float qi = st * b2.y - ct * (an.y * cp - an.x * sp);
            if (t < 63) b2 = make_float2(pr, pi);
            float2 qs;
            qs.x = __shfl_up(qr, 1); qs.y = __shfl_up(qi, 1);
            if (t >= 1) a = qs;
        }
    }

    const float* outph = (s == 0) ? outph1 : ((s == 1) ? outph2 : outph3);
    #pragma unroll
    for (int h = 0; h < 2; ++h) {
        const int j = 2 * t + h;
        float2 w = h ? b2 : a;
        float sp, cp; __sincosf(outph[j], &sp, &cp);
        const float wr = w.x * cp - w.y * sp;
        const float wi = w.x * sp + w.y * cp;
        const int cre = ((j >> 4) * 32) + (j & 15);
        if (s == 0) {
            P1[cre * 128 + r]        = f2bf(wr);
            P1[(cre + 16) * 128 + r] = f2bf(wi);
        } else {
            u16* P = (s == 1) ? P2 : P3;
            const int rre = ((r >> 4) * 32) + (r & 15);
            P[cre * 256 + rre]             = f2bf(wr);
            P[cre * 256 + rre + 16]        = f2bf(-wi);
            P[(cre + 16) * 256 + rre]      = f2bf(wi);
            P[(cre + 16) * 256 + rre + 16] = f2bf(wr);
        }
    }
}

// ---------------------------------------------------------------------------
// Main fused kernel. R18: cross the 64-reg occupancy cliff (m69: waves/CU
// halves at VGPR quanta 64/128/256 — R16/R17's 92 total regs capped the CU
// at 16 waves no matter what). Wave tile 32x32 (mt=2): acc 16 + A 8 +
// unroll-2 in-flight ~8 + addr/misc -> total ~60 <= the (512,8) 64-reg
// budget. 512 threads = 8 waves (1M x 8N), 32 rows/block, grid 2048,
// double-buffered zA 2x16KB. At 64 regs: 4 blocks x 8 waves = 32 waves/CU
// (2x R17) and 4 decorrelated barrier groups. Cost: B-traffic x2 (786MB L2
// ~ 23us spread) — covered by the doubled wave diversity.
// Numerics identical (f2bf + IEEE div + __expf).
// ---------------------------------------------------------------------------
__global__ __launch_bounds__(512, 8) void ficonn_mfma_kernel(
    const float* __restrict__ x,
    const u16* __restrict__ P1, const u16* __restrict__ P2,
    const u16* __restrict__ P3, const u16* __restrict__ P4,
    const float* __restrict__ al1, const float* __restrict__ be1,
    const float* __restrict__ al2, const float* __restrict__ be2,
    const float* __restrict__ bias, float* __restrict__ out)
{
    __shared__ __align__(16) char zBuf[2][16384];  // [32 rows][256 cols] bf16, swizzled
    char* const z0 = zBuf[0];
    char* const z1 = zBuf[1];

    const int tid  = threadIdx.x;
    const int lane = tid & 63;
    const int wv   = tid >> 6;        // 0..7 (N-split)
    const int l16  = lane & 15;
    const int kg   = lane >> 4;
    const int nb   = wv * 32;         // col base, stages 1-3
    const size_t rowBase = (size_t)blockIdx.x * 32;

    const int jf = wv * 16 + l16;     // this thread's complex feature
    const float av1 = 0.5f * fminf(fmaxf(al1[jf], 0.f), 10.f);
    const float bv1 = fminf(fmaxf(be1[jf], 0.f), 10.f);
    const float av2 = 0.5f * fminf(fmaxf(al2[jf], 0.f), 10.f);
    const float bv2 = fminf(fmaxf(be2[jf], 0.f), 10.f);

    // ---- stage x tile (32 rows x 128 cols fp32) into z0 as bf16, coalesced --
    {
        const float4* xg = (const float4*)(x + rowBase * 128);
        #pragma unroll
        for (int i = 0; i < 2; ++i) {
            const int idx = tid + i * 512;        // 0..1023
            const int row = idx >> 5;             // 32 float4 per row
            const int c4  = idx & 31;
            float4 f = xg[idx];
            uint2 v;
            v.x = (unsigned)f2bf(f.x) | ((unsigned)f2bf(f.y) << 16);
            v.y = (unsigned)f2bf(f.z) | ((unsigned)f2bf(f.w) << 16);
            const unsigned byte = ((unsigned)(row * 512 + c4 * 8)) ^ ((unsigned)(row & 31) << 4);
            *(uint2*)(z0 + byte) = v;
        }
    }
    __syncthreads();    // B1: x staged in z0

    f32x4 acc[2][2];

    // ================= stage 1: read z0 (x), B = P1, K=128 -> write z1 ======
    #pragma unroll
    for (int mt = 0; mt < 2; ++mt)
        #pragma unroll
        for (int nt = 0; nt < 2; ++nt) acc[mt][nt] = (f32x4){0.f, 0.f, 0.f, 0.f};

    #pragma unroll 2
    for (int ksl = 0; ksl < 4; ++ksl) {
        const int k0 = ksl * 32 + kg * 8;
        bf16x8 A[2];
        #pragma unroll
        for (int mt = 0; mt < 2; ++mt) {
            const int row = mt * 16 + l16;
            const unsigned byte = ((unsigned)(row * 512 + k0 * 2)) ^ ((unsigned)(row & 31) << 4);
            A[mt] = *(const bf16x8*)(z0 + byte);
        }
        #pragma unroll
        for (int nt = 0; nt < 2; ++nt) {
            bf16x8 Bf = *(const bf16x8*)&P1[(nb + nt * 16 + l16) * 128 + k0];
            #pragma unroll
            for (int mt = 0; mt < 2; ++mt)
                acc[mt][nt] = __builtin_amdgcn_mfma_f32_16x16x32_bf16(A[mt], Bf, acc[mt][nt], 0, 0, 0);
        }
    }

    // nofu1 + store to z1 (different buffer: no pre-barrier)
    #pragma unroll
    for (int mt = 0; mt < 2; ++mt)
        #pragma unroll
        for (int r = 0; r < 4; ++r) {
            float re = acc[mt][0][r], im = acc[mt][1][r];
            float I = fmaf(re, re, fmaf(im, im, 1e-8f));
            float fct = __expf(-av1 / fmaf(bv1, I, 1.f));
            re *= fct; im *= fct;
            const int row = mt * 16 + kg * 4 + r;
            const int colRe = nb + l16;
            const unsigned sw = (unsigned)(row & 31) << 4;
            *(u16*)(z1 + (((unsigned)(row * 512 + colRe * 2)) ^ sw)) = f2bf(re);
            *(u16*)(z1 + (((unsigned)(row * 512 + (colRe + 16) * 2)) ^ sw)) = f2bf(im);
        }
    __syncthreads();    // B2: z1 complete

    // ================= stage 2: read z1, B = P2, K=256 -> write z0 ==========
    #pragma unroll
    for (int mt = 0; mt < 2; ++mt)
        #pragma unroll
        for (int nt = 0; nt < 2; ++nt) acc[mt][nt] = (f32x4){0.f, 0.f, 0.f, 0.f};

    #pragma unroll 2
    for (int ks = 0; ks < 8; ++ks) {
        const int k0 = ks * 32 + kg * 8;
        bf16x8 A[2];
        #pragma unroll
        for (int mt = 0; mt < 2; ++mt) {
            const int row = mt * 16 + l16;
            const unsigned byte = ((unsigned)(row * 512 + k0 * 2)) ^ ((unsigned)(row & 31) << 4);
            A[mt] = *(const bf16x8*)(z1 + byte);
        }
        #pragma unroll
        for (int nt = 0; nt < 2; ++nt) {
            bf16x8 Bf = *(const bf16x8*)&P2[(nb + nt * 16 + l16) * 256 + k0];
            #pragma unroll
            for (int mt = 0; mt < 2; ++mt)
                acc[mt][nt] = __builtin_amdgcn_mfma_f32_16x16x32_bf16(A[mt], Bf, acc[mt][nt], 0, 0, 0);
        }
    }

    // nofu2 + store to z0
    #pragma unroll
    for (int mt = 0; mt < 2; ++mt)
        #pragma unroll
        for (int r = 0; r < 4; ++r) {
            float re = acc[mt][0][r], im = acc[mt][1][r];
            float I = fmaf(re, re, fmaf(im, im, 1e-8f));
            float fct = __expf(-av2 / fmaf(bv2, I, 1.f));
            re *= fct; im *= fct;
            const int row = mt * 16 + kg * 4 + r;
            const int colRe = nb + l16;
            const unsigned sw = (unsigned)(row & 31) << 4;
            *(u16*)(z0 + (((unsigned)(row * 512 + colRe * 2)) ^ sw)) = f2bf(re);
            *(u16*)(z0 + (((unsigned)(row * 512 + (colRe + 16) * 2)) ^ sw)) = f2bf(im);
        }
    __syncthreads();    // B3: z0 complete

    // ================= stage 3: read z0, B = P3, K=256 -> write z1 ==========
    #pragma unroll
    for (int mt = 0; mt < 2; ++mt)
        #pragma unroll
        for (int nt = 0; nt < 2; ++nt) acc[mt][nt] = (f32x4){0.f, 0.f, 0.f, 0.f};

    #pragma unroll 2
    for (int ks = 0; ks < 8; ++ks) {
        const int k0 = ks * 32 + kg * 8;
        bf16x8 A[2];
        #pragma unroll
        for (int mt = 0; mt < 2; ++mt) {
            const int row = mt * 16 + l16;
            const unsigned byte = ((unsigned)(row * 512 + k0 * 2)) ^ ((unsigned)(row & 31) << 4);
            A[mt] = *(const bf16x8*)(z0 + byte);
        }
        #pragma unroll
        for (int nt = 0; nt < 2; ++nt) {
            bf16x8 Bf = *(const bf16x8*)&P3[(nb + nt * 16 + l16) * 256 + k0];
            #pragma unroll
            for (int mt = 0; mt < 2; ++mt)
                acc[mt][nt] = __builtin_amdgcn_mfma_f32_16x16x32_bf16(A[mt], Bf, acc[mt][nt], 0, 0, 0);
        }
    }

    // store z3 (plain) to z1
    #pragma unroll
    for (int mt = 0; mt < 2; ++mt)
        #pragma unroll
        for (int r = 0; r < 4; ++r) {
            const int row = mt * 16 + kg * 4 + r;
            const int colRe = nb + l16;
            const unsigned sw = (unsigned)(row & 31) << 4;
            *(u16*)(z1 + (((unsigned)(row * 512 + colRe * 2)) ^ sw)) = f2bf(acc[mt][0][r]);
            *(u16*)(z1 + (((unsigned)(row * 512 + (colRe + 16) * 2)) ^ sw)) = f2bf(acc[mt][1][r]);
        }
    __syncthreads();    // B4: z1 complete

    // ================= final: read z1, B = P4 [128 cols][256 k] =============
    f32x4 facc[2];
    #pragma unroll
    for (int mt = 0; mt < 2; ++mt) facc[mt] = (f32x4){0.f, 0.f, 0.f, 0.f};

    const int nb2 = wv * 16;
    #pragma unroll 2
    for (int ks = 0; ks < 8; ++ks) {
        const int k0 = ks * 32 + kg * 8;
        bf16x8 A[2];
        #pragma unroll
        for (int mt = 0; mt < 2; ++mt) {
            const int row = mt * 16 + l16;
            const unsigned byte = ((unsigned)(row * 512 + k0 * 2)) ^ ((unsigned)(row & 31) << 4);
            A[mt] = *(const bf16x8*)(z1 + byte);
        }
        bf16x8 Bf = *(const bf16x8*)&P4[(nb2 + l16) * 256 + k0];
        #pragma unroll
        for (int mt = 0; mt < 2; ++mt)
            facc[mt] = __builtin_amdgcn_mfma_f32_16x16x32_bf16(A[mt], Bf, facc[mt], 0, 0, 0);
    }

    const float bcol = bias[nb2 + l16];
    #pragma unroll
    for (int mt = 0; mt < 2; ++mt)
        #pragma unroll
        for (int r = 0; r < 4; ++r) {
            const size_t row = rowBase + mt * 16 + kg * 4 + r;
            out[row * 128 + nb2 + l16] = facc[mt][r] + bcol;
        }
}

extern "C" void kernel_launch(void* const* d_in, const int* in_sizes, int n_in,
                              void* d_out, int out_size, void* d_ws, size_t ws_size,
                              hipStream_t stream)
{
    const float* x      = (const float*)d_in[0];
    const float* inph   = (const float*)d_in[1];
    const float* mzi1   = (const float*)d_in[2];
    const float* outph1 = (const float*)d_in[3];
    const float* alpha1 = (const float*)d_in[4];
    const float* beta1  = (const float*)d_in[5];
    const float* mzi2   = (const float*)d_in[6];
    const float* outph2 = (const float*)d_in[7];
    const float* alpha2 = (const float*)d_in[8];
    const float* beta2  = (const float*)d_in[9];
    const float* mzi3   = (const float*)d_in[10];
    const float* outph3 = (const float*)d_in[11];
    const float* W      = (const float*)d_in[12];
    const float* bias   = (const float*)d_in[13];

    const int B = in_sizes[0] / 128;

    // ws layout (trig table removed: sincos is inline in prep_all now)
    u16* P1 = (u16*)d_ws;                                  // 65536 B
    u16* P2 = P1 + 32768;                                  // 131072 B
    u16* P3 = P2 + 65536;                                  // 131072 B
    u16* P4 = P3 + 65536;                                  // 65536 B

    prep_all_kernel<<<512, 128, 0, stream>>>(
        mzi1, mzi2, mzi3, inph, outph1, outph2, outph3, W, P1, P2, P3, P4);
    ficonn_mfma_kernel<<<B / 32, 512, 0, stream>>>(
        x, P1, P2, P3, P4, alpha1, beta1, alpha2, beta2, bias, (float*)d_out);
}

// Round 19
// 82.748 us; speedup vs baseline: 1.4832x; 1.4832x over previous
//
#include <hip/hip_runtime.h>
#include <math.h>

typedef __attribute__((ext_vector_type(8))) short bf16x8;
typedef __attribute__((ext_vector_type(4))) float f32x4;
typedef unsigned short u16;

__device__ __forceinline__ unsigned short f2bf(float f) {
    unsigned u = __builtin_bit_cast(unsigned, f);
    u += 0x7fffu + ((u >> 16) & 1u);          // round-to-nearest-even
    return (unsigned short)(u >> 16);
}

// ---------------------------------------------------------------------------
// Fused prep (R18, correctness-proven): one kernel, 512 blocks x 128 threads.
//  b < 384 : build row r of mesh s (t<64 active) via register+shuffle layer
//            composition, sincos inline with a 4-deep mzi prefetch.
//  b >= 384: pack P4 from W.
// ---------------------------------------------------------------------------
__global__ __launch_bounds__(128) void prep_all_kernel(
    const float* __restrict__ mzi1, const float* __restrict__ mzi2,
    const float* __restrict__ mzi3, const float* __restrict__ inph,
    const float* __restrict__ outph1, const float* __restrict__ outph2,
    const float* __restrict__ outph3, const float* __restrict__ W,
    u16* __restrict__ P1, u16* __restrict__ P2, u16* __restrict__ P3,
    u16* __restrict__ P4)
{
    const int b = blockIdx.x, t = threadIdx.x;

    if (b >= 384) {                    // ---- P4 pack path ----
        const int n = b - 384;
        const int j = t;
        const int rre = ((j >> 4) * 32) + (j & 15);
        P4[n * 256 + rre]      = f2bf(W[n * 256 + j]);
        P4[n * 256 + rre + 16] = f2bf(W[n * 256 + j + 128]);
        return;
    }
    if (t >= 64) return;               // ---- build path: one wave ----

    const int s = b >> 7, r = b & 127;
    const float* mzi = (s == 0) ? mzi1 : ((s == 1) ? mzi2 : mzi3);

    float2 a = make_float2(0.f, 0.f), b2 = make_float2(0.f, 0.f);
    if (s == 0) {
        float sp, cp; __sincosf(inph[r], &sp, &cp);
        if (2 * t == r)     a  = make_float2(cp, sp);
        if (2 * t + 1 == r) b2 = make_float2(cp, sp);
    } else {
        if (2 * t == r)     a.x  = 1.f;
        if (2 * t + 1 == r) b2.x = 1.f;
    }

    auto ldmz = [&](int L) -> float2 {
        const int start = L & 1;
        const int m = 64 - start;
        if (t < m) {
            const int off = (L >> 1) * 254 + start * 128 + 2 * t;
            return *(const float2*)(mzi + off);
        }
        return make_float2(0.f, 0.f);
    };
    float2 mz[4];
    #pragma unroll
    for (int i = 0; i < 4; ++i) mz[i] = ldmz(i);

    #pragma unroll 4
    for (int L = 0; L < 128; ++L) {
        const float2 v = mz[L & 3];
        if (L < 124) mz[L & 3] = ldmz(L + 4);
        float st, ct, sp, cp;
        __sincosf(v.x, &st, &ct);
        __sincosf(v.y, &sp, &cp);
        if ((L & 1) == 0) {
            float pr = ct * (a.x * cp - a.y * sp) + st * b2.x;
            float pi = ct * (a.x * sp + a.y * cp) + st * b2.y;
            float qr = st * a.x - ct * (b2.x * cp + b2.y * sp);
            float qi = st * a.y - ct * (b2.y * cp - b2.x * sp);
            a = make_float2(pr, pi); b2 = make_float2(qr, qi);
        } else {
            float2 an;
            an.x = __shfl_down(a.x, 1); an.y = __shfl_down(a.y, 1);
            float pr = ct * (b2.x * cp - b2.y * sp) + st * an.x;
            float pi = ct * (b2.x * sp + b2.y * cp) + st * an.y;
            float qr = st * b2.x - ct * (an.x * cp + an.y * sp);
            float qi = st * b2.y - ct * (an.y * cp - an.x * sp);
            if (t < 63) b2 = make_float2(pr, pi);
            float2 qs;
            qs.x = __shfl_up(qr, 1); qs.y = __shfl_up(qi, 1);
            if (t >= 1) a = qs;
        }
    }

    const float* outph = (s == 0) ? outph1 : ((s == 1) ? outph2 : outph3);
    #pragma unroll
    for (int h = 0; h < 2; ++h) {
        const int j = 2 * t + h;
        float2 w = h ? b2 : a;
        float sp, cp; __sincosf(outph[j], &sp, &cp);
        const float wr = w.x * cp - w.y * sp;
        const float wi = w.x * sp + w.y * cp;
        const int cre = ((j >> 4) * 32) + (j & 15);
        if (s == 0) {
            P1[cre * 128 + r]        = f2bf(wr);
            P1[(cre + 16) * 128 + r] = f2bf(wi);
        } else {
            u16* P = (s == 1) ? P2 : P3;
            const int rre = ((r >> 4) * 32) + (r & 15);
            P[cre * 256 + rre]             = f2bf(wr);
            P[cre * 256 + rre + 16]        = f2bf(-wi);
            P[(cre + 16) * 256 + rre]      = f2bf(wi);
            P[(cre + 16) * 256 + rre + 16] = f2bf(wr);
        }
    }
}

// ---------------------------------------------------------------------------
// Main fused kernel. R19 = R17 (best: 512 threads = 8 narrow waves 1M x 8N,
// wave tile 64x32, 64 rows/block, unroll-2 k-loops, double-buffered zA
// 2x32KB, (512,4) -> 60 arch VGPR spill-free, 16 waves/CU) with ONE change:
// nofu's IEEE division replaced by __fdividef (v_rcp_f32 + mul, ~2 ops vs
// ~15). Denominator 1+bv*I >= 1 -> no fast-path edge cases. VALU was the
// busiest pipe (28%); div was its largest per-element consumer.
// R18 post-mortem: (512,8) 64-reg budget -> allocator capped arch at 32,
// spilled 44MB; occupancy 85% but 115us. 65-128 band + zero spill is the
// confirmed optimum; both neighbors of the reg quantum are worse.
// ---------------------------------------------------------------------------
__global__ __launch_bounds__(512, 4) void ficonn_mfma_kernel(
    const float* __restrict__ x,
    const u16* __restrict__ P1, const u16* __restrict__ P2,
    const u16* __restrict__ P3, const u16* __restrict__ P4,
    const float* __restrict__ al1, const float* __restrict__ be1,
    const float* __restrict__ al2, const float* __restrict__ be2,
    const float* __restrict__ bias, float* __restrict__ out)
{
    __shared__ __align__(16) char zBuf[2][32768];  // [64 rows][256 cols] bf16 each, swizzled
    char* const z0 = zBuf[0];
    char* const z1 = zBuf[1];

    const int tid  = threadIdx.x;
    const int lane = tid & 63;
    const int wv   = tid >> 6;        // 0..7 (N-split)
    const int l16  = lane & 15;
    const int kg   = lane >> 4;
    const int nb   = wv * 32;         // col base, stages 1-3
    const size_t rowBase = (size_t)blockIdx.x * 64;

    const int jf = wv * 16 + l16;     // this thread's complex feature
    const float av1 = 0.5f * fminf(fmaxf(al1[jf], 0.f), 10.f);
    const float bv1 = fminf(fmaxf(be1[jf], 0.f), 10.f);
    const float av2 = 0.5f * fminf(fmaxf(al2[jf], 0.f), 10.f);
    const float bv2 = fminf(fmaxf(be2[jf], 0.f), 10.f);

    // ---- stage x tile (64 rows x 128 cols fp32) into z0 as bf16, coalesced --
    {
        const float4* xg = (const float4*)(x + rowBase * 128);
        #pragma unroll
        for (int i = 0; i < 4; ++i) {
            const int idx = tid + i * 512;        // 0..2047
            const int row = idx >> 5;             // 32 float4 per row
            const int c4  = idx & 31;
            float4 f = xg[idx];
            uint2 v;
            v.x = (unsigned)f2bf(f.x) | ((unsigned)f2bf(f.y) << 16);
            v.y = (unsigned)f2bf(f.z) | ((unsigned)f2bf(f.w) << 16);
            const unsigned byte = ((unsigned)(row * 512 + c4 * 8)) ^ ((unsigned)(row & 31) << 4);
            *(uint2*)(z0 + byte) = v;
        }
    }
    __syncthreads();    // B1: x staged in z0

    f32x4 acc[4][2];

    // ================= stage 1: read z0 (x), B = P1, K=128 -> write z1 ======
    #pragma unroll
    for (int mt = 0; mt < 4; ++mt)
        #pragma unroll
        for (int nt = 0; nt < 2; ++nt) acc[mt][nt] = (f32x4){0.f, 0.f, 0.f, 0.f};

    #pragma unroll 2
    for (int ksl = 0; ksl < 4; ++ksl) {
        const int k0 = ksl * 32 + kg * 8;
        bf16x8 A[4];
        #pragma unroll
        for (int mt = 0; mt < 4; ++mt) {
            const int row = mt * 16 + l16;
            const unsigned byte = ((unsigned)(row * 512 + k0 * 2)) ^ ((unsigned)(row & 31) << 4);
            A[mt] = *(const bf16x8*)(z0 + byte);
        }
        #pragma unroll
        for (int nt = 0; nt < 2; ++nt) {
            bf16x8 Bf = *(const bf16x8*)&P1[(nb + nt * 16 + l16) * 128 + k0];
            #pragma unroll
            for (int mt = 0; mt < 4; ++mt)
                acc[mt][nt] = __builtin_amdgcn_mfma_f32_16x16x32_bf16(A[mt], Bf, acc[mt][nt], 0, 0, 0);
        }
    }

    // nofu1 + store to z1 (different buffer: no pre-barrier)
    #pragma unroll
    for (int mt = 0; mt < 4; ++mt)
        #pragma unroll
        for (int r = 0; r < 4; ++r) {
            float re = acc[mt][0][r], im = acc[mt][1][r];
            float I = fmaf(re, re, fmaf(im, im, 1e-8f));
            float fct = __expf(__fdividef(-av1, fmaf(bv1, I, 1.f)));
            re *= fct; im *= fct;
            const int row = mt * 16 + kg * 4 + r;
            const int colRe = nb + l16;
            const unsigned sw = (unsigned)(row & 31) << 4;
            *(u16*)(z1 + (((unsigned)(row * 512 + colRe * 2)) ^ sw)) = f2bf(re);
            *(u16*)(z1 + (((unsigned)(row * 512 + (colRe + 16) * 2)) ^ sw)) = f2bf(im);
        }
    __syncthreads();    // B2: z1 complete

    // ================= stage 2: read z1, B = P2, K=256 -> write z0 ==========
    #pragma unroll
    for (int mt = 0; mt < 4; ++mt)
        #pragma unroll
        for (int nt = 0; nt < 2; ++nt) acc[mt][nt] = (f32x4){0.f, 0.f, 0.f, 0.f};

    #pragma unroll 2
    for (int ks = 0; ks < 8; ++ks) {
        const int k0 = ks * 32 + kg * 8;
        bf16x8 A[4];
        #pragma unroll
        for (int mt = 0; mt < 4; ++mt) {
            const int row = mt * 16 + l16;
            const unsigned byte = ((unsigned)(row * 512 + k0 * 2)) ^ ((unsigned)(row & 31) << 4);
            A[mt] = *(const bf16x8*)(z1 + byte);
        }
        #pragma unroll
        for (int nt = 0; nt < 2; ++nt) {
            bf16x8 Bf = *(const bf16x8*)&P2[(nb + nt * 16 + l16) * 256 + k0];
            #pragma unroll
            for (int mt = 0; mt < 4; ++mt)
                acc[mt][nt] = __builtin_amdgcn_mfma_f32_16x16x32_bf16(A[mt], Bf, acc[mt][nt], 0, 0, 0);
        }
    }

    // nofu2 + store to z0
    #pragma unroll
    for (int mt = 0; mt < 4; ++mt)
        #pragma unroll
        for (int r = 0; r < 4; ++r) {
            float re = acc[mt][0][r], im = acc[mt][1][r];
            float I = fmaf(re, re, fmaf(im, im, 1e-8f));
            float fct = __expf(__fdividef(-av2, fmaf(bv2, I, 1.f)));
            re *= fct; im *= fct;
            const int row = mt * 16 + kg * 4 + r;
            const int colRe = nb + l16;
            const unsigned sw = (unsigned)(row & 31) << 4;
            *(u16*)(z0 + (((unsigned)(row * 512 + colRe * 2)) ^ sw)) = f2bf(re);
            *(u16*)(z0 + (((unsigned)(row * 512 + (colRe + 16) * 2)) ^ sw)) = f2bf(im);
        }
    __syncthreads();    // B3: z0 complete

    // ================= stage 3: read z0, B = P3, K=256 -> write z1 ==========
    #pragma unroll
    for (int mt = 0; mt < 4; ++mt)
        #pragma unroll
        for (int nt = 0; nt < 2; ++nt) acc[mt][nt] = (f32x4){0.f, 0.f, 0.f, 0.f};

    #pragma unroll 2
    for (int ks = 0; ks < 8; ++ks) {
        const int k0 = ks * 32 + kg * 8;
        bf16x8 A[4];
        #pragma unroll
        for (int mt = 0; mt < 4; ++mt) {
            const int row = mt * 16 + l16;
            const unsigned byte = ((unsigned)(row * 512 + k0 * 2)) ^ ((unsigned)(row & 31) << 4);
            A[mt] = *(const bf16x8*)(z0 + byte);
        }
        #pragma unroll
        for (int nt = 0; nt < 2; ++nt) {
            bf16x8 Bf = *(const bf16x8*)&P3[(nb + nt * 16 + l16) * 256 + k0];
            #pragma unroll
            for (int mt = 0; mt < 4; ++mt)
                acc[mt][nt] = __builtin_amdgcn_mfma_f32_16x16x32_bf16(A[mt], Bf, acc[mt][nt], 0, 0, 0);
        }
    }

    // store z3 (plain) to z1
    #pragma unroll
    for (int mt = 0; mt < 4; ++mt)
        #pragma unroll
        for (int r = 0; r < 4; ++r) {
            const int row = mt * 16 + kg * 4 + r;
            const int colRe = nb + l16;
            const unsigned sw = (unsigned)(row & 31) << 4;
            *(u16*)(z1 + (((unsigned)(row * 512 + colRe * 2)) ^ sw)) = f2bf(acc[mt][0][r]);
            *(u16*)(z1 + (((unsigned)(row * 512 + (colRe + 16) * 2)) ^ sw)) = f2bf(acc[mt][1][r]);
        }
    __syncthreads();    // B4: z1 complete

    // ================= final: read z1, B = P4 [128 cols][256 k] =============
    f32x4 facc[4];
    #pragma unroll
    for (int mt = 0; mt < 4; ++mt) facc[mt] = (f32x4){0.f, 0.f, 0.f, 0.f};

    const int nb2 = wv * 16;
    #pragma unroll 2
    for (int ks = 0; ks < 8; ++ks) {
        const int k0 = ks * 32 + kg * 8;
        bf16x8 A[4];
        #pragma unroll
        for (int mt = 0; mt < 4; ++mt) {
            const int row = mt * 16 + l16;
            const unsigned byte = ((unsigned)(row * 512 + k0 * 2)) ^ ((unsigned)(row & 31) << 4);
            A[mt] = *(const bf16x8*)(z1 + byte);
        }
        bf16x8 Bf = *(const bf16x8*)&P4[(nb2 + l16) * 256 + k0];
        #pragma unroll
        for (int mt = 0; mt < 4; ++mt)
            facc[mt] = __builtin_amdgcn_mfma_f32_16x16x32_bf16(A[mt], Bf, facc[mt], 0, 0, 0);
    }

    const float bcol = bias[nb2 + l16];
    #pragma unroll
    for (int mt = 0; mt < 4; ++mt)
        #pragma unroll
        for (int r = 0; r < 4; ++r) {
            const size_t row = rowBase + mt * 16 + kg * 4 + r;
            out[row * 128 + nb2 + l16] = facc[mt][r] + bcol;
        }
}

extern "C" void kernel_launch(void* const* d_in, const int* in_sizes, int n_in,
                              void* d_out, int out_size, void* d_ws, size_t ws_size,
                              hipStream_t stream)
{
    const float* x      = (const float*)d_in[0];
    const float* inph   = (const float*)d_in[1];
    const float* mzi1   = (const float*)d_in[2];
    const float* outph1 = (const float*)d_in[3];
    const float* alpha1 = (const float*)d_in[4];
    const float* beta1  = (const float*)d_in[5];
    const float* mzi2   = (const float*)d_in[6];
    const float* outph2 = (const float*)d_in[7];
    const float* alpha2 = (const float*)d_in[8];
    const float* beta2  = (const float*)d_in[9];
    const float* mzi3   = (const float*)d_in[10];
    const float* outph3 = (const float*)d_in[11];
    const float* W      = (const float*)d_in[12];
    const float* bias   = (const float*)d_in[13];

    const int B = in_sizes[0] / 128;

    // ws layout (no trig table: sincos inline in prep_all)
    u16* P1 = (u16*)d_ws;                                  // 65536 B
    u16* P2 = P1 + 32768;                                  // 131072 B
    u16* P3 = P2 + 65536;                                  // 131072 B
    u16* P4 = P3 + 65536;                                  // 65536 B

    prep_all_kernel<<<512, 128, 0, stream>>>(
        mzi1, mzi2, mzi3, inph, outph1, outph2, outph3, W, P1, P2, P3, P4);
    ficonn_mfma_kernel<<<B / 64, 512, 0, stream>>>(
        x, P1, P2, P3, P4, alpha1, beta1, alpha2, beta2, bias, (float*)d_out);
}